// Round 7
// baseline (397.383 us; speedup 1.0000x reference)
//
#include <hip/hip_runtime.h>
#include <hip/hip_bf16.h>
#include <math.h>

// 3-layer GCN on MI355X.
// R10: agg->gemm layer fusion. agg's 64-node output tile is exactly the
//   64-row input tile of the next gemm block => fuse with zero cross-block
//   deps. Middle layers run as ONE kernel: agg into LDS XT[feat][node]
//   (fp32, never hits HBM), syncthreads, 4x4-blocked gemm -> bf16 hs.
//   Kills per-boundary 25MB fp32 write + 12.8MB read + a dispatch gap.
//   hs double-buffered: hsbA in ws, hsbB aliased into d_out (dead until
//   final agg3, which reads hsbA only). 11 -> 9 dispatches.
//   Build chain unchanged from R9 (bucket partition @1024thr + LDS-int adjw).

#define FDIM 64
#define BKT 128              // nodes per bucket
#define MAXNB 1024           // max buckets supported (N <= 131072)

typedef float f32x2 __attribute__((ext_vector_type(2)));

// ---------- build: bucket partition ----------

__global__ __launch_bounds__(1024) void partA_kernel(const int* __restrict__ ecol,
                                                     int* __restrict__ gcnt,
                                                     int e, int nb, int epb) {
    __shared__ int lh[MAXNB];
    const int t = threadIdx.x;
    for (int i = t; i < nb; i += 1024) lh[i] = 0;
    __syncthreads();
    int s = blockIdx.x * epb;
    int en = s + epb; if (en > e) en = e;
    for (int i = s + t; i < en; i += 1024) atomicAdd(&lh[ecol[i] >> 7], 1);
    __syncthreads();
    for (int i = t; i < nb; i += 1024)
        if (lh[i]) atomicAdd(&gcnt[i], lh[i]);
}

__global__ __launch_bounds__(1024) void scan_kernel(const int* __restrict__ gcnt,
                                                    int* __restrict__ base,
                                                    int* __restrict__ cursor, int nb) {
    __shared__ int s[1024];
    const int t = threadIdx.x;
    int v = (t < nb) ? gcnt[t] : 0;
    s[t] = v;
    __syncthreads();
    for (int off = 1; off < 1024; off <<= 1) {
        int x = (t >= off) ? s[t - off] : 0;
        __syncthreads();
        s[t] += x;
        __syncthreads();
    }
    int incl = s[t];
    if (t < nb) { base[t] = incl - v; cursor[t] = incl - v; }
    if (t == nb - 1) base[nb] = incl;
}

__global__ __launch_bounds__(1024) void partB_kernel(const int* __restrict__ erow,
                                                     const int* __restrict__ ecol,
                                                     int* __restrict__ cursor,
                                                     unsigned* __restrict__ part,
                                                     int e, int nb, int epb) {
    __shared__ int lh[MAXNB];
    __shared__ int lbase[MAXNB];
    const int t = threadIdx.x;
    for (int i = t; i < nb; i += 1024) lh[i] = 0;
    __syncthreads();
    int s = blockIdx.x * epb;
    int en = s + epb; if (en > e) en = e;
    for (int i = s + t; i < en; i += 1024) atomicAdd(&lh[ecol[i] >> 7], 1);
    __syncthreads();
    for (int i = t; i < nb; i += 1024)
        lbase[i] = lh[i] ? atomicAdd(&cursor[i], lh[i]) : 0;
    __syncthreads();
    for (int i = t; i < nb; i += 1024) lh[i] = 0;
    __syncthreads();
    for (int i = s + t; i < en; i += 1024) {
        int c = ecol[i];
        int b = c >> 7;
        int off = atomicAdd(&lh[b], 1);
        part[lbase[b] + off] = ((unsigned)erow[i] << 7) | (unsigned)(c & 127);
    }
}

// per-bucket: partitioned edges -> fixed-stride adjacency + per-node degree.
__global__ __launch_bounds__(256) void adjw_kernel(const unsigned* __restrict__ part,
                                                   const int* __restrict__ base,
                                                   int* __restrict__ cnt,
                                                   int* __restrict__ adjF,
                                                   int n, int cap) {
    const int b = blockIdx.x;
    const int v0 = b << 7;
    __shared__ int lc[BKT];
    const int t = threadIdx.x;
    if (t < BKT) lc[t] = 0;
    __syncthreads();
    const int s0 = base[b], s1 = base[b + 1];
    for (int e = s0 + t; e < s1; e += 256) {
        unsigned pk = part[e];
        int c = pk & 127;
        int slot = atomicAdd(&lc[c], 1);
        if (slot < cap) adjF[(size_t)(v0 + c) * cap + slot] = (int)(pk >> 7);
    }
    __syncthreads();
    int nn = n - v0; if (nn > BKT) nn = BKT;
    if (t < nn) cnt[v0 + t] = lc[t];
}

// ---------- per-layer compute ----------

// Hs[n,64] = bf16( rsqrt(cnt+1) * (X[n,64] @ W[64,64]) )  (layer 1 from fp32 x)
__global__ __launch_bounds__(256) void gemm_kernel(const float* __restrict__ X,
                                                   const float* __restrict__ W,
                                                   const int* __restrict__ cnt,
                                                   __hip_bfloat16* __restrict__ Hout, int n) {
    __shared__ float XT[64][68];
    __shared__ float Ws[64][68];
    const int t = threadIdx.x;
    const int row0 = blockIdx.x * 64;
    #pragma unroll
    for (int i = t; i < 4096; i += 256) Ws[i >> 6][i & 63] = W[i];
    #pragma unroll
    for (int i = t; i < 4096; i += 256) {
        int r = i >> 6, c = i & 63;
        int gr = row0 + r;
        XT[c][r] = (gr < n) ? X[(size_t)gr * FDIM + c] : 0.0f;   // coalesced read
    }
    __syncthreads();

    const int tc = t & 15;        // col block
    const int tr = t >> 4;        // row block
    float acc[4][4];
    #pragma unroll
    for (int i = 0; i < 4; i++)
        #pragma unroll
        for (int j = 0; j < 4; j++) acc[i][j] = 0.0f;

    #pragma unroll 8
    for (int k = 0; k < 64; k++) {
        float4 a = *(const float4*)&XT[k][4 * tr];
        float4 b = *(const float4*)&Ws[k][4 * tc];
        acc[0][0] += a.x * b.x; acc[0][1] += a.x * b.y; acc[0][2] += a.x * b.z; acc[0][3] += a.x * b.w;
        acc[1][0] += a.y * b.x; acc[1][1] += a.y * b.y; acc[1][2] += a.y * b.z; acc[1][3] += a.y * b.w;
        acc[2][0] += a.z * b.x; acc[2][1] += a.z * b.y; acc[2][2] += a.z * b.z; acc[2][3] += a.z * b.w;
        acc[3][0] += a.w * b.x; acc[3][1] += a.w * b.y; acc[3][2] += a.w * b.z; acc[3][3] += a.w * b.w;
    }

    #pragma unroll
    for (int i = 0; i < 4; i++) {
        int gr = row0 + 4 * tr + i;
        if (gr < n) {
            float dv = rsqrtf((float)cnt[gr] + 1.0f);   // +1 self loop
            union { ushort4 u; __hip_bfloat16 h[4]; } pk;
            pk.h[0] = __float2bfloat16(acc[i][0] * dv);
            pk.h[1] = __float2bfloat16(acc[i][1] * dv);
            pk.h[2] = __float2bfloat16(acc[i][2] * dv);
            pk.h[3] = __float2bfloat16(acc[i][3] * dv);
            *(ushort4*)&Hout[(size_t)gr * FDIM + 4 * tc] = pk.u;   // 8B coalesced
        }
    }
}

__device__ inline f32x2 bf2f(unsigned u) {
    f32x2 r;
    r.x = __uint_as_float(u << 16);
    r.y = __uint_as_float(u & 0xffff0000u);
    return r;
}

__device__ inline void unpack_add(uint4 w, f32x2* a) {
    a[0] += bf2f(w.x);      // v_pk_add_f32
    a[1] += bf2f(w.y);
    a[2] += bf2f(w.z);
    a[3] += bf2f(w.w);
}

// Gather + accumulate one node v for the calling wave. Returns a[4] on all
// lanes; es==0 lanes hold the final 8-feature slice after reduce.
__device__ inline void agg_node(int v, int lane, int sl, int es, int deg, int cap,
                                const uint4* __restrict__ hs4,
                                const int* __restrict__ adjF,
                                const int* __restrict__ erow,
                                const int* __restrict__ ecol, int etot,
                                f32x2* a) {
    #pragma unroll
    for (int j = 0; j < 4; j++) a[j] = (f32x2)(0.0f);

    // self loop (once: es==0 group covers all 8 slices)
    if (es == 0) {
        uint4 w = hs4[(size_t)v * 8 + sl];
        unpack_add(w, a);
    }

    if (deg <= cap) {                       // fast path (always, in practice)
        const int* __restrict__ av = adjF + (size_t)v * cap;
        for (int base = 0; base < deg; base += 64) {
            int m = deg - base; if (m > 64) m = 64;
            int uvec = 0;
            if (lane < m) uvec = av[base + lane];        // coalesced
            int g = 0;
            for (; g + 16 <= m; g += 16) {               // 2 edges/lane-group per iter
                int u0 = __shfl(uvec, g + es, 64);
                int u1 = __shfl(uvec, g + 8 + es, 64);
                uint4 w0 = hs4[(size_t)u0 * 8 + sl];
                uint4 w1 = hs4[(size_t)u1 * 8 + sl];
                unpack_add(w0, a);
                unpack_add(w1, a);
            }
            for (; g < m; g += 8) {
                int idx = g + es;
                int u = __shfl(uvec, (idx < m) ? idx : 0, 64);
                if (idx < m) {
                    uint4 w = hs4[(size_t)u * 8 + sl];
                    unpack_add(w, a);
                }
            }
        }
    } else {
        // slow path: deg > cap (prob ~0) — wave-cooperative scan of raw edges
        for (int base = 0; base < etot; base += 64) {
            int m = etot - base; if (m > 64) m = 64;
            int c = -1, r = 0;
            if (lane < m) { c = ecol[base + lane]; r = erow[base + lane]; }
            unsigned long long mask = __ballot(c == v);
            while (mask) {
                int j = __ffsll((long long)mask) - 1;
                mask &= mask - 1;
                int u = __shfl(r, j, 64);
                if (es == 0) {
                    uint4 w = hs4[(size_t)u * 8 + sl];
                    unpack_add(w, a);
                }
            }
        }
    }

    // reduce across the 8 edge slots (lanes sl, sl+8, ..., sl+56)
    #pragma unroll
    for (int off = 8; off < 64; off <<= 1) {
        #pragma unroll
        for (int j = 0; j < 4; j++) {
            f32x2 o;
            o.x = __shfl_xor(a[j].x, off, 64);
            o.y = __shfl_xor(a[j].y, off, 64);
            a[j] += o;                                   // v_pk_add_f32
        }
    }
}

// Fused middle layer: agg(hs_in)+bias+ELU for 64 nodes -> LDS XT[feat][node]
// -> 4x4-blocked gemm @ W -> bf16 hs_out (scaled by dinv). No fp32 HBM
// round-trip, one kernel instead of two.
__global__ __launch_bounds__(256) void fused_kernel(const __hip_bfloat16* __restrict__ hs_in,
                                                    const int* __restrict__ adjF,
                                                    const int* __restrict__ cnt,
                                                    const float* __restrict__ bias,
                                                    const float* __restrict__ W,
                                                    __hip_bfloat16* __restrict__ hs_out,
                                                    int n, int cap,
                                                    const int* __restrict__ erow,
                                                    const int* __restrict__ ecol, int etot) {
    __shared__ float XT[64][68];     // [feat][node_local]; stride 68 keeps float4 align
    __shared__ float Ws[64][64];
    const int t = threadIdx.x;
    const int row0 = blockIdx.x * 64;

    // stage W while agg's gathers are in flight
    #pragma unroll
    for (int i = t; i < 4096; i += 256) Ws[i >> 6][i & 63] = W[i];

    const int lane = t & 63;
    const int wv = t >> 6;          // wave 0..3
    const int sl = lane & 7;        // feature slice
    const int es = lane >> 3;       // edge slot
    const uint4* __restrict__ hs4 = (const uint4*)hs_in;

    // ---- agg phase: this wave handles nodes row0 + wv*16 + (0..15) ----
    for (int it = 0; it < 16; ++it) {
        int v = row0 + wv * 16 + it;
        if (v >= n) break;                       // wave-uniform
        int deg = cnt[v];
        f32x2 a[4];
        agg_node(v, lane, sl, es, deg, cap, hs4, adjF, erow, ecol, etot, a);
        if (es == 0) {
            float dv = rsqrtf((float)deg + 1.0f);
            const f32x2* b2 = (const f32x2*)&bias[8 * sl];
            int c = wv * 16 + it;
            #pragma unroll
            for (int j = 0; j < 4; j++) {
                f32x2 r = a[j] * dv + b2[j];
                float r0 = (r.x > 0.0f) ? r.x : (__expf(r.x) - 1.0f);   // ELU
                float r1 = (r.y > 0.0f) ? r.y : (__expf(r.y) - 1.0f);
                XT[8 * sl + 2 * j][c] = r0;
                XT[8 * sl + 2 * j + 1][c] = r1;
            }
        }
    }
    __syncthreads();

    // ---- gemm phase: Hs_out[row0+r][:] = bf16( dinv * (XT^T @ W) ) ----
    const int tc = t & 15;
    const int tr = t >> 4;
    float acc[4][4];
    #pragma unroll
    for (int i = 0; i < 4; i++)
        #pragma unroll
        for (int j = 0; j < 4; j++) acc[i][j] = 0.0f;

    #pragma unroll 8
    for (int k = 0; k < 64; k++) {
        float4 a = *(const float4*)&XT[k][4 * tr];
        float4 b = *(const float4*)&Ws[k][4 * tc];
        acc[0][0] += a.x * b.x; acc[0][1] += a.x * b.y; acc[0][2] += a.x * b.z; acc[0][3] += a.x * b.w;
        acc[1][0] += a.y * b.x; acc[1][1] += a.y * b.y; acc[1][2] += a.y * b.z; acc[1][3] += a.y * b.w;
        acc[2][0] += a.z * b.x; acc[2][1] += a.z * b.y; acc[2][2] += a.z * b.z; acc[2][3] += a.z * b.w;
        acc[3][0] += a.w * b.x; acc[3][1] += a.w * b.y; acc[3][2] += a.w * b.z; acc[3][3] += a.w * b.w;
    }

    #pragma unroll
    for (int i = 0; i < 4; i++) {
        int gr = row0 + 4 * tr + i;
        if (gr < n) {
            float dv = rsqrtf((float)cnt[gr] + 1.0f);
            union { ushort4 u; __hip_bfloat16 h[4]; } pk;
            pk.h[0] = __float2bfloat16(acc[i][0] * dv);
            pk.h[1] = __float2bfloat16(acc[i][1] * dv);
            pk.h[2] = __float2bfloat16(acc[i][2] * dv);
            pk.h[3] = __float2bfloat16(acc[i][3] * dv);
            *(ushort4*)&hs_out[(size_t)gr * FDIM + 4 * tc] = pk.u;
        }
    }
}

// Final layer: agg + bias (no ELU) -> fp32 out. Wave per node.
__global__ __launch_bounds__(256) void agg_kernel(const __hip_bfloat16* __restrict__ hs,
                                                  const int* __restrict__ adjF,
                                                  const int* __restrict__ cnt,
                                                  const float* __restrict__ bias,
                                                  float* __restrict__ out,
                                                  int n, int cap,
                                                  const int* __restrict__ erow,
                                                  const int* __restrict__ ecol, int etot) {
    const int v = blockIdx.x * 4 + (threadIdx.x >> 6);
    const int lane = threadIdx.x & 63;
    if (v >= n) return;
    const int sl = lane & 7;
    const int es = lane >> 3;
    const int deg = cnt[v];
    const float dv = rsqrtf((float)deg + 1.0f);
    const uint4* __restrict__ hs4 = (const uint4*)hs;

    f32x2 a[4];
    agg_node(v, lane, sl, es, deg, cap, hs4, adjF, erow, ecol, etot, a);

    if (es == 0) {
        const f32x2* b2 = (const f32x2*)&bias[8 * sl];
        float r[8];
        #pragma unroll
        for (int j = 0; j < 4; j++) {
            f32x2 tv = a[j] * dv + b2[j];
            r[2 * j] = tv.x;
            r[2 * j + 1] = tv.y;
        }
        float4* op = (float4*)&out[(size_t)v * FDIM + 8 * sl];
        op[0] = make_float4(r[0], r[1], r[2], r[3]);
        op[1] = make_float4(r[4], r[5], r[6], r[7]);
    }
}

// ---------- launch ----------

extern "C" void kernel_launch(void* const* d_in, const int* in_sizes, int n_in,
                              void* d_out, int out_size, void* d_ws, size_t ws_size,
                              hipStream_t stream) {
    const float* x   = (const float*)d_in[0];
    const int*   ei  = (const int*)d_in[1];
    const float* W1  = (const float*)d_in[2];
    const float* b1  = (const float*)d_in[3];
    const float* W2  = (const float*)d_in[4];
    const float* b2  = (const float*)d_in[5];
    const float* W3  = (const float*)d_in[6];
    const float* b3  = (const float*)d_in[7];

    const int N = in_sizes[0] / FDIM;      // 100000
    const int E = in_sizes[1] / 2;         // 1600000
    const int* erow = ei;                   // sources
    const int* ecol = ei + E;               // targets

    const int NB = (N + BKT - 1) / BKT;    // 782 buckets

    char* p = (char*)d_ws;
    __hip_bfloat16* hsbA = (__hip_bfloat16*)p;  p += (size_t)N * FDIM * sizeof(__hip_bfloat16); // 12.8 MB
    int*   cnt  = (int*)p;   p += (size_t)N * sizeof(int);
    int* gcnt   = (int*)p;   p += (size_t)(NB + 1) * sizeof(int);
    int* bbase  = (int*)p;   p += (size_t)(NB + 1) * sizeof(int);
    int* cursor = (int*)p;   p += (size_t)(NB + 1) * sizeof(int);
    int*   adjF = (int*)p;

    // part[] aliases hsbA (dead before gemm1 writes it).
    unsigned* part = (unsigned*)hsbA;
    // hsbB aliases d_out: used only between fused1 (write) and fused2 (read);
    // final agg reads hsbA and overwrites d_out with fp32 output.
    __hip_bfloat16* hsbB = (__hip_bfloat16*)d_out;

    // adjacency capacity: biggest of {64,48,32} that fits the workspace
    size_t used = (size_t)(p - (char*)d_ws);
    int cap = 64;
    while (cap > 32 && used + (size_t)N * cap * sizeof(int) > ws_size) cap -= 16;

    float* outb = (float*)d_out;

    const int TB = 256;
    const int PBLK = 512;                        // partition blocks (1024 thr each)
    const int epb = (E + PBLK - 1) / PBLK;       // edges per partition block
    const int nblkG = (N + 63) / 64;
    const int nblkA = (N + 3) / 4;

    hipMemsetAsync(gcnt, 0, (size_t)(NB + 1) * sizeof(int), stream);
    partA_kernel<<<PBLK, 1024, 0, stream>>>(ecol, gcnt, E, NB, epb);
    scan_kernel<<<1, 1024, 0, stream>>>(gcnt, bbase, cursor, NB);
    partB_kernel<<<PBLK, 1024, 0, stream>>>(erow, ecol, cursor, part, E, NB, epb);
    adjw_kernel<<<NB, TB, 0, stream>>>(part, bbase, cnt, adjF, N, cap);

    gemm_kernel<<<nblkG, TB, 0, stream>>>(x, W1, cnt, hsbA, N);
    fused_kernel<<<nblkG, TB, 0, stream>>>(hsbA, adjF, cnt, b1, W2, hsbB, N, cap, erow, ecol, E);
    fused_kernel<<<nblkG, TB, 0, stream>>>(hsbB, adjF, cnt, b2, W3, hsbA, N, cap, erow, ecol, E);
    agg_kernel<<<nblkA, TB, 0, stream>>>(hsbA, adjF, cnt, b3, outb, N, cap, erow, ecol, E);
}

// Round 9
// 327.762 us; speedup vs baseline: 1.2124x; 1.2124x over previous
//
#include <hip/hip_runtime.h>
#include <hip/hip_bf16.h>
#include <math.h>

// 3-layer GCN on MI355X.
// R11 (resubmit — prior round died on GPU acquisition, never ran):
//   fusion reverted (R10: 33KB LDS halved occupancy of the latency-bound
//   gather -> 99us; agg needs max waves). Build shortened: partA+scan
//   ELIMINATED — buckets get fixed regions of BCAP=4080 (+45 sigma over the
//   2046 mean), partB scatters via cursor-relative offsets directly.
//   Exactness net: overflow edges (prob ~0) counted in extra[]; adjw writes
//   cnt = -(true deg) for tainted nodes -> agg slow path (exact), dinv from
//   |cnt| everywhere. 11 -> 9 dispatches.

#define FDIM 64
#define BKT 128              // nodes per bucket
#define MAXNB 1024           // max buckets supported (N <= 131072)
#define BCAP 4080            // fixed edges-per-bucket region (mean 2046, sd 45)

typedef float f32x2 __attribute__((ext_vector_type(2)));

// ---------- build ----------

// Scatter edges into fixed per-bucket regions. No partA/scan needed.
__global__ __launch_bounds__(1024) void partB_kernel(const int* __restrict__ erow,
                                                     const int* __restrict__ ecol,
                                                     int* __restrict__ cursor,
                                                     int* __restrict__ extra,
                                                     unsigned* __restrict__ part,
                                                     int e, int nb, int epb) {
    __shared__ int lh[MAXNB];
    __shared__ int lbase[MAXNB];
    const int t = threadIdx.x;
    for (int i = t; i < nb; i += 1024) lh[i] = 0;
    __syncthreads();
    int s = blockIdx.x * epb;
    int en = s + epb; if (en > e) en = e;
    for (int i = s + t; i < en; i += 1024) atomicAdd(&lh[ecol[i] >> 7], 1);
    __syncthreads();
    for (int i = t; i < nb; i += 1024)
        lbase[i] = lh[i] ? atomicAdd(&cursor[i], lh[i]) : 0;
    __syncthreads();
    for (int i = t; i < nb; i += 1024) lh[i] = 0;
    __syncthreads();
    for (int i = s + t; i < en; i += 1024) {
        int c = ecol[i];
        int b = c >> 7;
        int pos = lbase[b] + atomicAdd(&lh[b], 1);
        if (pos < BCAP) part[(size_t)b * BCAP + pos] = ((unsigned)erow[i] << 7) | (unsigned)(c & 127);
        else atomicAdd(&extra[c], 1);            // overflow edge (prob ~0): count it
    }
}

// per-bucket: partitioned edges -> fixed-stride adjacency + exact degree.
// Tainted nodes (bucket overflow) get cnt = -deg -> agg slow path.
__global__ __launch_bounds__(256) void adjw_kernel(const unsigned* __restrict__ part,
                                                   const int* __restrict__ cursor,
                                                   const int* __restrict__ extra,
                                                   int* __restrict__ cnt,
                                                   int* __restrict__ adjF,
                                                   int n, int cap) {
    const int b = blockIdx.x;
    const int v0 = b << 7;
    __shared__ int lc[BKT];
    const int t = threadIdx.x;
    if (t < BKT) lc[t] = 0;
    __syncthreads();
    int tot = cursor[b];
    int s1 = (tot < BCAP) ? tot : BCAP;
    const unsigned* __restrict__ pb = part + (size_t)b * BCAP;
    for (int e = t; e < s1; e += 256) {
        unsigned pk = pb[e];
        int c = pk & 127;
        int slot = atomicAdd(&lc[c], 1);
        if (slot < cap) adjF[(size_t)(v0 + c) * cap + slot] = (int)(pk >> 7);
    }
    __syncthreads();
    int nn = n - v0; if (nn > BKT) nn = BKT;
    if (t < nn) {
        int ex = extra[v0 + t];
        int d = lc[t] + ex;
        cnt[v0 + t] = (ex > 0) ? -d : d;     // negative = tainted -> slow path
    }
}

// ---------- per-layer compute ----------

// Hs[n,64] = bf16( rsqrt(|cnt|+1) * (X[n,64] @ W[64,64]) )
__global__ __launch_bounds__(256) void gemm_kernel(const float* __restrict__ X,
                                                   const float* __restrict__ W,
                                                   const int* __restrict__ cnt,
                                                   __hip_bfloat16* __restrict__ Hout, int n) {
    __shared__ float XT[64][68];
    __shared__ float Ws[64][68];
    const int t = threadIdx.x;
    const int row0 = blockIdx.x * 64;
    #pragma unroll
    for (int i = t; i < 4096; i += 256) Ws[i >> 6][i & 63] = W[i];
    #pragma unroll
    for (int i = t; i < 4096; i += 256) {
        int r = i >> 6, c = i & 63;
        int gr = row0 + r;
        XT[c][r] = (gr < n) ? X[(size_t)gr * FDIM + c] : 0.0f;   // coalesced read
    }
    __syncthreads();

    const int tc = t & 15;        // col block
    const int tr = t >> 4;        // row block
    float acc[4][4];
    #pragma unroll
    for (int i = 0; i < 4; i++)
        #pragma unroll
        for (int j = 0; j < 4; j++) acc[i][j] = 0.0f;

    #pragma unroll 8
    for (int k = 0; k < 64; k++) {
        float4 a = *(const float4*)&XT[k][4 * tr];
        float4 b = *(const float4*)&Ws[k][4 * tc];
        acc[0][0] += a.x * b.x; acc[0][1] += a.x * b.y; acc[0][2] += a.x * b.z; acc[0][3] += a.x * b.w;
        acc[1][0] += a.y * b.x; acc[1][1] += a.y * b.y; acc[1][2] += a.y * b.z; acc[1][3] += a.y * b.w;
        acc[2][0] += a.z * b.x; acc[2][1] += a.z * b.y; acc[2][2] += a.z * b.z; acc[2][3] += a.z * b.w;
        acc[3][0] += a.w * b.x; acc[3][1] += a.w * b.y; acc[3][2] += a.w * b.z; acc[3][3] += a.w * b.w;
    }

    #pragma unroll
    for (int i = 0; i < 4; i++) {
        int gr = row0 + 4 * tr + i;
        if (gr < n) {
            float dv = rsqrtf(fabsf((float)cnt[gr]) + 1.0f);   // |cnt| + self loop
            union { ushort4 u; __hip_bfloat16 h[4]; } pk;
            pk.h[0] = __float2bfloat16(acc[i][0] * dv);
            pk.h[1] = __float2bfloat16(acc[i][1] * dv);
            pk.h[2] = __float2bfloat16(acc[i][2] * dv);
            pk.h[3] = __float2bfloat16(acc[i][3] * dv);
            *(ushort4*)&Hout[(size_t)gr * FDIM + 4 * tc] = pk.u;   // 8B coalesced
        }
    }
}

__device__ inline f32x2 bf2f(unsigned u) {
    f32x2 r;
    r.x = __uint_as_float(u << 16);
    r.y = __uint_as_float(u & 0xffff0000u);
    return r;
}

__device__ inline void unpack_add(uint4 w, f32x2* a) {
    a[0] += bf2f(w.x);      // v_pk_add_f32
    a[1] += bf2f(w.y);
    a[2] += bf2f(w.z);
    a[3] += bf2f(w.w);
}

// out[v][:] = dinv(v) * ( hs[v][:] + sum_{u in N_in(v)} hs[u][:] ) + b ; optional ELU.
// Wave per node. 8 lanes x 16B per edge. Packed f32x2 accumulation,
// shfl_xor tree reduce over the 8 edge slots.
__global__ __launch_bounds__(256) void agg_kernel(const __hip_bfloat16* __restrict__ hs,
                                                  const int* __restrict__ adjF,
                                                  const int* __restrict__ cnt,
                                                  const float* __restrict__ bias,
                                                  float* __restrict__ out,
                                                  int n, int cap, int do_elu,
                                                  const int* __restrict__ erow,
                                                  const int* __restrict__ ecol, int etot) {
    const int v = blockIdx.x * 4 + (threadIdx.x >> 6);
    const int lane = threadIdx.x & 63;
    if (v >= n) return;
    const int sl = lane & 7;       // feature slice (16B = 8 bf16)
    const int es = lane >> 3;      // edge slot 0..7
    const int deg_raw = cnt[v];
    const int deg = (deg_raw < 0) ? -deg_raw : deg_raw;
    const float dv = rsqrtf((float)deg + 1.0f);         // +1 self loop
    const uint4* __restrict__ hs4 = (const uint4*)hs;

    f32x2 a[4];
    #pragma unroll
    for (int j = 0; j < 4; j++) a[j] = (f32x2)(0.0f);

    // self loop (once: es==0 group covers all 8 slices)
    if (es == 0) {
        uint4 w = hs4[(size_t)v * 8 + sl];
        unpack_add(w, a);
    }

    if (deg_raw >= 0 && deg_raw <= cap) {   // fast path (always, in practice)
        const int* __restrict__ av = adjF + (size_t)v * cap;
        int m = deg;
        int uvec = 0;
        if (lane < m) uvec = av[lane];               // coalesced
        int g = 0;
        for (; g + 16 <= m; g += 16) {               // 2 edges/lane-group per iter
            int u0 = __shfl(uvec, g + es, 64);
            int u1 = __shfl(uvec, g + 8 + es, 64);
            uint4 w0 = hs4[(size_t)u0 * 8 + sl];
            uint4 w1 = hs4[(size_t)u1 * 8 + sl];
            unpack_add(w0, a);
            unpack_add(w1, a);
        }
        for (; g < m; g += 8) {
            int idx = g + es;
            int u = __shfl(uvec, (idx < m) ? idx : 0, 64);
            if (idx < m) {
                uint4 w = hs4[(size_t)u * 8 + sl];
                unpack_add(w, a);
            }
        }
    } else {
        // slow path: deg > cap or tainted (prob ~0) — exact full-edge scan
        for (int base = 0; base < etot; base += 64) {
            int m = etot - base; if (m > 64) m = 64;
            int c = -1, r = 0;
            if (lane < m) { c = ecol[base + lane]; r = erow[base + lane]; }
            unsigned long long mask = __ballot(c == v);
            while (mask) {
                int j = __ffsll((long long)mask) - 1;
                mask &= mask - 1;
                int u = __shfl(r, j, 64);
                if (es == 0) {
                    uint4 w = hs4[(size_t)u * 8 + sl];
                    unpack_add(w, a);
                }
            }
        }
    }

    // reduce across the 8 edge slots (lanes sl, sl+8, ..., sl+56)
    #pragma unroll
    for (int off = 8; off < 64; off <<= 1) {
        #pragma unroll
        for (int j = 0; j < 4; j++) {
            f32x2 o;
            o.x = __shfl_xor(a[j].x, off, 64);
            o.y = __shfl_xor(a[j].y, off, 64);
            a[j] += o;                               // v_pk_add_f32
        }
    }

    if (es == 0) {
        const f32x2* b2 = (const f32x2*)&bias[8 * sl];
        float r[8];
        #pragma unroll
        for (int j = 0; j < 4; j++) {
            f32x2 tv = a[j] * dv + b2[j];
            r[2 * j] = tv.x;
            r[2 * j + 1] = tv.y;
        }
        if (do_elu) {
            #pragma unroll
            for (int j = 0; j < 8; j++)
                r[j] = (r[j] > 0.0f) ? r[j] : (__expf(r[j]) - 1.0f);
        }
        float4* op = (float4*)&out[(size_t)v * FDIM + 8 * sl];
        op[0] = make_float4(r[0], r[1], r[2], r[3]);
        op[1] = make_float4(r[4], r[5], r[6], r[7]);
    }
}

// ---------- launch ----------

extern "C" void kernel_launch(void* const* d_in, const int* in_sizes, int n_in,
                              void* d_out, int out_size, void* d_ws, size_t ws_size,
                              hipStream_t stream) {
    const float* x   = (const float*)d_in[0];
    const int*   ei  = (const int*)d_in[1];
    const float* W1  = (const float*)d_in[2];
    const float* b1  = (const float*)d_in[3];
    const float* W2  = (const float*)d_in[4];
    const float* b2  = (const float*)d_in[5];
    const float* W3  = (const float*)d_in[6];
    const float* b3  = (const float*)d_in[7];

    const int N = in_sizes[0] / FDIM;      // 100000
    const int E = in_sizes[1] / 2;         // 1600000
    const int* erow = ei;                   // sources
    const int* ecol = ei + E;               // targets

    const int NB = (N + BKT - 1) / BKT;    // 782 buckets

    char* p = (char*)d_ws;
    __hip_bfloat16* hsb = (__hip_bfloat16*)p;  p += (size_t)N * FDIM * sizeof(__hip_bfloat16); // 12.8 MB
    int*   cnt  = (int*)p;   p += (size_t)N * sizeof(int);
    int* cursor = (int*)p;   p += (size_t)(NB + 1) * sizeof(int);   // cursor+extra contiguous
    int* extra  = (int*)p;   p += (size_t)N * sizeof(int);          // (one memset covers both)
    int*   adjF = (int*)p;

    // part[] aliases hsb: NB*BCAP*4 = 12.76MB <= N*128B = 12.8MB; dead before
    // gemm1 writes hsb.
    unsigned* part = (unsigned*)hsb;

    // adjacency capacity: biggest of {64,48,32} that fits the workspace
    size_t used = (size_t)(p - (char*)d_ws);
    int cap = 64;
    while (cap > 32 && used + (size_t)N * cap * sizeof(int) > ws_size) cap -= 16;

    float* outb = (float*)d_out;

    const int TB = 256;
    const int PBLK = 256;                        // partition blocks (1024 thr each)
    const int epb = (E + PBLK - 1) / PBLK;       // edges per partition block
    const int nblkG = (N + 63) / 64;
    const int nblkA = (N + 3) / 4;

    hipMemsetAsync(cursor, 0, (size_t)(NB + 1 + N) * sizeof(int), stream);
    partB_kernel<<<PBLK, 1024, 0, stream>>>(erow, ecol, cursor, extra, part, E, NB, epb);
    adjw_kernel<<<NB, TB, 0, stream>>>(part, cursor, extra, cnt, adjF, N, cap);

    gemm_kernel<<<nblkG, TB, 0, stream>>>(x, W1, cnt, hsb, N);
    agg_kernel<<<nblkA, TB, 0, stream>>>(hsb, adjF, cnt, b1, outb, N, cap, 1, erow, ecol, E);
    gemm_kernel<<<nblkG, TB, 0, stream>>>(outb, W2, cnt, hsb, N);
    agg_kernel<<<nblkA, TB, 0, stream>>>(hsb, adjF, cnt, b2, outb, N, cap, 1, erow, ecol, E);
    gemm_kernel<<<nblkG, TB, 0, stream>>>(outb, W3, cnt, hsb, N);
    agg_kernel<<<nblkA, TB, 0, stream>>>(hsb, adjF, cnt, b3, outb, N, cap, 0, erow, ecol, E);
}

// Round 10
// 320.434 us; speedup vs baseline: 1.2401x; 1.0229x over previous
//
#include <hip/hip_runtime.h>
#include <hip/hip_bf16.h>
#include <math.h>

// 3-layer GCN on MI355X.
// R12: agg restructured — 2 nodes/wave, 32 lanes/node, lane = f32x2 feature
//   pair, sequential edge loop with width-32 shfl broadcast of the edge idx.
//   Kills the 36-inst shfl_xor reduce + 7/8-idle epilogue of the 8-slot
//   layout (~88 -> ~55 wave-inst per node). Gather = one coalesced 128B
//   request per edge. Build chain + gemm unchanged from R11.

#define FDIM 64
#define BKT 128              // nodes per bucket
#define MAXNB 1024           // max buckets supported (N <= 131072)
#define BCAP 4080            // fixed edges-per-bucket region (mean 2046, sd 45)

typedef float f32x2 __attribute__((ext_vector_type(2)));

// ---------- build ----------

// Scatter edges into fixed per-bucket regions. No partA/scan needed.
__global__ __launch_bounds__(1024) void partB_kernel(const int* __restrict__ erow,
                                                     const int* __restrict__ ecol,
                                                     int* __restrict__ cursor,
                                                     int* __restrict__ extra,
                                                     unsigned* __restrict__ part,
                                                     int e, int nb, int epb) {
    __shared__ int lh[MAXNB];
    __shared__ int lbase[MAXNB];
    const int t = threadIdx.x;
    for (int i = t; i < nb; i += 1024) lh[i] = 0;
    __syncthreads();
    int s = blockIdx.x * epb;
    int en = s + epb; if (en > e) en = e;
    for (int i = s + t; i < en; i += 1024) atomicAdd(&lh[ecol[i] >> 7], 1);
    __syncthreads();
    for (int i = t; i < nb; i += 1024)
        lbase[i] = lh[i] ? atomicAdd(&cursor[i], lh[i]) : 0;
    __syncthreads();
    for (int i = t; i < nb; i += 1024) lh[i] = 0;
    __syncthreads();
    for (int i = s + t; i < en; i += 1024) {
        int c = ecol[i];
        int b = c >> 7;
        int pos = lbase[b] + atomicAdd(&lh[b], 1);
        if (pos < BCAP) part[(size_t)b * BCAP + pos] = ((unsigned)erow[i] << 7) | (unsigned)(c & 127);
        else atomicAdd(&extra[c], 1);            // overflow edge (prob ~0): count it
    }
}

// per-bucket: partitioned edges -> fixed-stride adjacency + exact degree.
// Tainted nodes (bucket overflow) get cnt = -deg -> agg slow path.
__global__ __launch_bounds__(256) void adjw_kernel(const unsigned* __restrict__ part,
                                                   const int* __restrict__ cursor,
                                                   const int* __restrict__ extra,
                                                   int* __restrict__ cnt,
                                                   int* __restrict__ adjF,
                                                   int n, int cap) {
    const int b = blockIdx.x;
    const int v0 = b << 7;
    __shared__ int lc[BKT];
    const int t = threadIdx.x;
    if (t < BKT) lc[t] = 0;
    __syncthreads();
    int tot = cursor[b];
    int s1 = (tot < BCAP) ? tot : BCAP;
    const unsigned* __restrict__ pb = part + (size_t)b * BCAP;
    for (int e = t; e < s1; e += 256) {
        unsigned pk = pb[e];
        int c = pk & 127;
        int slot = atomicAdd(&lc[c], 1);
        if (slot < cap) adjF[(size_t)(v0 + c) * cap + slot] = (int)(pk >> 7);
    }
    __syncthreads();
    int nn = n - v0; if (nn > BKT) nn = BKT;
    if (t < nn) {
        int ex = extra[v0 + t];
        int d = lc[t] + ex;
        cnt[v0 + t] = (ex > 0) ? -d : d;     // negative = tainted -> slow path
    }
}

// ---------- per-layer compute ----------

// Hs[n,64] = bf16( rsqrt(|cnt|+1) * (X[n,64] @ W[64,64]) )
__global__ __launch_bounds__(256) void gemm_kernel(const float* __restrict__ X,
                                                   const float* __restrict__ W,
                                                   const int* __restrict__ cnt,
                                                   __hip_bfloat16* __restrict__ Hout, int n) {
    __shared__ float XT[64][68];
    __shared__ float Ws[64][68];
    const int t = threadIdx.x;
    const int row0 = blockIdx.x * 64;
    #pragma unroll
    for (int i = t; i < 4096; i += 256) Ws[i >> 6][i & 63] = W[i];
    #pragma unroll
    for (int i = t; i < 4096; i += 256) {
        int r = i >> 6, c = i & 63;
        int gr = row0 + r;
        XT[c][r] = (gr < n) ? X[(size_t)gr * FDIM + c] : 0.0f;   // coalesced read
    }
    __syncthreads();

    const int tc = t & 15;        // col block
    const int tr = t >> 4;        // row block
    float acc[4][4];
    #pragma unroll
    for (int i = 0; i < 4; i++)
        #pragma unroll
        for (int j = 0; j < 4; j++) acc[i][j] = 0.0f;

    #pragma unroll 8
    for (int k = 0; k < 64; k++) {
        float4 a = *(const float4*)&XT[k][4 * tr];
        float4 b = *(const float4*)&Ws[k][4 * tc];
        acc[0][0] += a.x * b.x; acc[0][1] += a.x * b.y; acc[0][2] += a.x * b.z; acc[0][3] += a.x * b.w;
        acc[1][0] += a.y * b.x; acc[1][1] += a.y * b.y; acc[1][2] += a.y * b.z; acc[1][3] += a.y * b.w;
        acc[2][0] += a.z * b.x; acc[2][1] += a.z * b.y; acc[2][2] += a.z * b.z; acc[2][3] += a.z * b.w;
        acc[3][0] += a.w * b.x; acc[3][1] += a.w * b.y; acc[3][2] += a.w * b.z; acc[3][3] += a.w * b.w;
    }

    #pragma unroll
    for (int i = 0; i < 4; i++) {
        int gr = row0 + 4 * tr + i;
        if (gr < n) {
            float dv = rsqrtf(fabsf((float)cnt[gr]) + 1.0f);   // |cnt| + self loop
            union { ushort4 u; __hip_bfloat16 h[4]; } pk;
            pk.h[0] = __float2bfloat16(acc[i][0] * dv);
            pk.h[1] = __float2bfloat16(acc[i][1] * dv);
            pk.h[2] = __float2bfloat16(acc[i][2] * dv);
            pk.h[3] = __float2bfloat16(acc[i][3] * dv);
            *(ushort4*)&Hout[(size_t)gr * FDIM + 4 * tc] = pk.u;   // 8B coalesced
        }
    }
}

__device__ inline f32x2 bf2f(unsigned u) {
    f32x2 r;
    r.x = __uint_as_float(u << 16);
    r.y = __uint_as_float(u & 0xffff0000u);
    return r;
}

// out[v][:] = dinv(v) * ( hs[v][:] + sum_{u in N_in(v)} hs[u][:] ) + b ; opt ELU.
// 2 nodes per wave: 32 lanes/node, lane = f32x2 feature pair (owns it for ALL
// edges -> no reduction). Edge idx broadcast via width-32 shfl; gather =
// one coalesced 128B request per edge.
__global__ __launch_bounds__(256) void agg_kernel(const __hip_bfloat16* __restrict__ hs,
                                                  const int* __restrict__ adjF,
                                                  const int* __restrict__ cnt,
                                                  const float* __restrict__ bias,
                                                  float* __restrict__ out,
                                                  int n, int cap, int do_elu,
                                                  const int* __restrict__ erow,
                                                  const int* __restrict__ ecol, int etot) {
    const int tid = threadIdx.x;
    const int v = blockIdx.x * 8 + (tid >> 5);
    const int lane32 = tid & 31;             // feature pair 0..31
    const int half = (tid >> 5) & 1;         // which half of the wave
    const bool alive = v < n;
    const unsigned* __restrict__ hsu = (const unsigned*)hs;

    int deg_raw = alive ? cnt[v] : 0;
    int deg = (deg_raw < 0) ? -deg_raw : deg_raw;
    bool slow = alive && (deg_raw < 0 || deg > cap);

    f32x2 a = (f32x2)(0.0f);
    if (alive) a = bf2f(hsu[(size_t)v * 32 + lane32]);          // self loop

    if (alive && !slow) {                    // fast path (always, in practice)
        const int* __restrict__ av = adjF + (size_t)v * cap;
        for (int base = 0; base < deg; base += 32) {
            int mc = deg - base; if (mc > 32) mc = 32;
            int uvec = 0;
            if (lane32 < mc) uvec = av[base + lane32];           // coalesced
            int g = 0;
            for (; g + 8 <= mc; g += 8) {
                int u0 = __shfl(uvec, g + 0, 32);
                int u1 = __shfl(uvec, g + 1, 32);
                int u2 = __shfl(uvec, g + 2, 32);
                int u3 = __shfl(uvec, g + 3, 32);
                int u4 = __shfl(uvec, g + 4, 32);
                int u5 = __shfl(uvec, g + 5, 32);
                int u6 = __shfl(uvec, g + 6, 32);
                int u7 = __shfl(uvec, g + 7, 32);
                unsigned w0 = hsu[(size_t)u0 * 32 + lane32];
                unsigned w1 = hsu[(size_t)u1 * 32 + lane32];
                unsigned w2 = hsu[(size_t)u2 * 32 + lane32];
                unsigned w3 = hsu[(size_t)u3 * 32 + lane32];
                unsigned w4 = hsu[(size_t)u4 * 32 + lane32];
                unsigned w5 = hsu[(size_t)u5 * 32 + lane32];
                unsigned w6 = hsu[(size_t)u6 * 32 + lane32];
                unsigned w7 = hsu[(size_t)u7 * 32 + lane32];
                a += bf2f(w0); a += bf2f(w1); a += bf2f(w2); a += bf2f(w3);
                a += bf2f(w4); a += bf2f(w5); a += bf2f(w6); a += bf2f(w7);
            }
            for (; g + 4 <= mc; g += 4) {
                int u0 = __shfl(uvec, g + 0, 32);
                int u1 = __shfl(uvec, g + 1, 32);
                int u2 = __shfl(uvec, g + 2, 32);
                int u3 = __shfl(uvec, g + 3, 32);
                unsigned w0 = hsu[(size_t)u0 * 32 + lane32];
                unsigned w1 = hsu[(size_t)u1 * 32 + lane32];
                unsigned w2 = hsu[(size_t)u2 * 32 + lane32];
                unsigned w3 = hsu[(size_t)u3 * 32 + lane32];
                a += bf2f(w0); a += bf2f(w1); a += bf2f(w2); a += bf2f(w3);
            }
            for (; g < mc; g++) {
                int u = __shfl(uvec, g, 32);
                a += bf2f(hsu[(size_t)u * 32 + lane32]);
            }
        }
    }
    if (__any(slow)) {
        // slow path: deg > cap or tainted (prob ~0) — exact full-edge scan.
        // Both halves scan the same 32-edge window, each vs its own v.
        for (int base = 0; base < etot; base += 32) {
            int m = etot - base; if (m > 32) m = 32;
            int c = -1, r = 0;
            if (lane32 < m) { c = ecol[base + lane32]; r = erow[base + lane32]; }
            unsigned long long b = __ballot(slow && (c == v));
            unsigned bh = (unsigned)(b >> (half * 32));
            while (bh) {
                int j = __ffs(bh) - 1;
                bh &= bh - 1;
                int u = __shfl(r, j, 32);
                if (slow) a += bf2f(hsu[(size_t)u * 32 + lane32]);
            }
        }
    }

    if (alive) {
        float dv = rsqrtf((float)deg + 1.0f);       // +1 self loop
        f32x2 bv = ((const f32x2*)bias)[lane32];
        f32x2 rr = a * dv + bv;
        float rx = rr.x, ry = rr.y;
        if (do_elu) {
            rx = (rx > 0.0f) ? rx : (__expf(rx) - 1.0f);
            ry = (ry > 0.0f) ? ry : (__expf(ry) - 1.0f);
        }
        ((float2*)out)[(size_t)v * 32 + lane32] = make_float2(rx, ry);
    }
}

// ---------- launch ----------

extern "C" void kernel_launch(void* const* d_in, const int* in_sizes, int n_in,
                              void* d_out, int out_size, void* d_ws, size_t ws_size,
                              hipStream_t stream) {
    const float* x   = (const float*)d_in[0];
    const int*   ei  = (const int*)d_in[1];
    const float* W1  = (const float*)d_in[2];
    const float* b1  = (const float*)d_in[3];
    const float* W2  = (const float*)d_in[4];
    const float* b2  = (const float*)d_in[5];
    const float* W3  = (const float*)d_in[6];
    const float* b3  = (const float*)d_in[7];

    const int N = in_sizes[0] / FDIM;      // 100000
    const int E = in_sizes[1] / 2;         // 1600000
    const int* erow = ei;                   // sources
    const int* ecol = ei + E;               // targets

    const int NB = (N + BKT - 1) / BKT;    // 782 buckets

    char* p = (char*)d_ws;
    __hip_bfloat16* hsb = (__hip_bfloat16*)p;  p += (size_t)N * FDIM * sizeof(__hip_bfloat16); // 12.8 MB
    int*   cnt  = (int*)p;   p += (size_t)N * sizeof(int);
    int* cursor = (int*)p;   p += (size_t)(NB + 1) * sizeof(int);   // cursor+extra contiguous
    int* extra  = (int*)p;   p += (size_t)N * sizeof(int);          // (one memset covers both)
    int*   adjF = (int*)p;

    // part[] aliases hsb: NB*BCAP*4 = 12.76MB <= N*128B = 12.8MB; dead before
    // gemm1 writes hsb.
    unsigned* part = (unsigned*)hsb;

    // adjacency capacity: biggest of {64,48,32} that fits the workspace
    size_t used = (size_t)(p - (char*)d_ws);
    int cap = 64;
    while (cap > 32 && used + (size_t)N * cap * sizeof(int) > ws_size) cap -= 16;

    float* outb = (float*)d_out;

    const int TB = 256;
    const int PBLK = 256;                        // partition blocks (1024 thr each)
    const int epb = (E + PBLK - 1) / PBLK;       // edges per partition block
    const int nblkG = (N + 63) / 64;
    const int nblkA = (N + 7) / 8;               // 8 nodes per 256-thread block

    hipMemsetAsync(cursor, 0, (size_t)(NB + 1 + N) * sizeof(int), stream);
    partB_kernel<<<PBLK, 1024, 0, stream>>>(erow, ecol, cursor, extra, part, E, NB, epb);
    adjw_kernel<<<NB, TB, 0, stream>>>(part, cursor, extra, cnt, adjF, N, cap);

    gemm_kernel<<<nblkG, TB, 0, stream>>>(x, W1, cnt, hsb, N);
    agg_kernel<<<nblkA, TB, 0, stream>>>(hsb, adjF, cnt, b1, outb, N, cap, 1, erow, ecol, E);
    gemm_kernel<<<nblkG, TB, 0, stream>>>(outb, W2, cnt, hsb, N);
    agg_kernel<<<nblkA, TB, 0, stream>>>(hsb, adjF, cnt, b2, outb, N, cap, 1, erow, ecol, E);
    gemm_kernel<<<nblkG, TB, 0, stream>>>(outb, W3, cnt, hsb, N);
    agg_kernel<<<nblkA, TB, 0, stream>>>(hsb, adjF, cnt, b3, outb, N, cap, 0, erow, ecol, E);
}